// Round 10
// baseline (147.903 us; speedup 1.0000x reference)
//
#include <hip/hip_runtime.h>
#include <math.h>

// bf16-MFMA MHA v10: flash rebuilt around KV-SLAB SPLIT — wave w owns kv rows
// [16w,16w+16) of every tile and covers ALL 64 q of the block. Eliminates the
// 4x cross-wave K/V fragment-read redundancy (v9: 256 B/lane per 16qx64kv;
// v10: 64 B/lane per 64qx16kv). PV runs K=32 over tile-PAIRS (composite
// k = 8hi+(e&3)+4(e>>2) maps two tiles' slab scores directly onto the verified
// 16x16x32 A-fragment — kappa collapses to identity). V triple-buffered (pair
// must outlive next prefetch). Partial (acc,l) merged across waves by simple
// addition (no-max softmax => merge is exact). Head-pinned grid (v8-proven).
// GEMMs: T2 swizzle + 2-phase dbuf (v7, unchanged).
// MFMA 16x16x32 bf16 layouts (HW-verified, learn_hip m89/m92):
//   A frag: lane holds A[l&15][8*(l>>4)+e], e=0..7 (k-contiguous bf16x8)
//   B frag: lane holds B[8*(l>>4)+e][l&15]
//   C/D:    lane reg r -> C[(l>>4)*4 + r][l&15]

namespace {

constexpr int kHID = 1024;
constexpr int kNH  = 16;
constexpr int kHD  = 64;
constexpr int kSEQ = 2048;

// 1/sqrt(64) * log2(e): scores in log2 domain -> raw exp2f softmax.
constexpr float kQScale = 0.125f * 1.4426950408889634f;

typedef unsigned short ushortT;
typedef __attribute__((ext_vector_type(8))) short   bf16x8;
typedef __attribute__((ext_vector_type(4))) short   bf16x4;
typedef __attribute__((ext_vector_type(4))) float   f32x4;
typedef __attribute__((ext_vector_type(4))) unsigned short u16x4;

#define MFMA(a, b, c) __builtin_amdgcn_mfma_f32_16x16x32_bf16((a), (b), (c), 0, 0, 0)

typedef const __attribute__((address_space(1))) void GVoid;
typedef __attribute__((address_space(3))) void SVoid;

__device__ __forceinline__ void gload_lds16(const ushortT* g, ushortT* l) {
    __builtin_amdgcn_global_load_lds((GVoid*)g, (SVoid*)l, 16, 0, 0);
}

__device__ __forceinline__ ushortT f2bf(float f) {
    unsigned u = __builtin_bit_cast(unsigned, f);
    u += 0x7fffu + ((u >> 16) & 1u);
    return (ushortT)(u >> 16);
}

__device__ __forceinline__ unsigned cvt_pk_bf16(float a, float b) {
    unsigned r;
    asm("v_cvt_pk_bf16_f32 %0, %1, %2" : "=v"(r) : "v"(a), "v"(b));
    return r;  // low half = bf16(a), high half = bf16(b)
}

__device__ __forceinline__ float4 ld4f(const float* p) { return *reinterpret_cast<const float4*>(p); }

// ---------------------------------------------------------------------------
// x fp32 -> bf16
// ---------------------------------------------------------------------------
__global__ __launch_bounds__(256) void cvtx_kernel(const float* __restrict__ x,
                                                   ushortT* __restrict__ xb) {
    const size_t i = ((size_t)blockIdx.x * 256 + threadIdx.x) * 4;
    const float4 f = ld4f(&x[i]);
    u16x4 o = { f2bf(f.x), f2bf(f.y), f2bf(f.z), f2bf(f.w) };
    *reinterpret_cast<u16x4*>(&xb[i]) = o;
}

// ---------------------------------------------------------------------------
// W[k][n] fp32 -> Wt[n][k] bf16, 64x64 tiles via LDS. z selects matrix.
// ---------------------------------------------------------------------------
__global__ __launch_bounds__(256) void transw_kernel(
    const float* __restrict__ W0, const float* __restrict__ W1,
    const float* __restrict__ W2, const float* __restrict__ W3,
    ushortT* __restrict__ WtAll) {
    __shared__ ushortT T[64 * 72];
    const float* W = (blockIdx.z == 0) ? W0 : (blockIdx.z == 1) ? W1 : (blockIdx.z == 2) ? W2 : W3;
    ushortT* Wt = WtAll + (size_t)blockIdx.z * kHID * kHID;
    const int kb = blockIdx.y * 64, nb = blockIdx.x * 64;
    const int tid = threadIdx.x;
    {
        const int kr = tid >> 2, nc = (tid & 3) * 16;
        #pragma unroll
        for (int i = 0; i < 16; i += 4) {
            const float4 f = ld4f(&W[(size_t)(kb + kr) * kHID + nb + nc + i]);
            T[kr * 72 + nc + i + 0] = f2bf(f.x);
            T[kr * 72 + nc + i + 1] = f2bf(f.y);
            T[kr * 72 + nc + i + 2] = f2bf(f.z);
            T[kr * 72 + nc + i + 3] = f2bf(f.w);
        }
    }
    __syncthreads();
    {
        const int nr = tid >> 2, kc = (tid & 3) * 16;
        ushortT tmp[16];
        #pragma unroll
        for (int i = 0; i < 16; ++i) tmp[i] = T[(kc + i) * 72 + nr];
        *reinterpret_cast<bf16x8*>(&Wt[(size_t)(nb + nr) * kHID + kb + kc]) =
            *reinterpret_cast<bf16x8*>(&tmp[0]);
        *reinterpret_cast<bf16x8*>(&Wt[(size_t)(nb + nr) * kHID + kb + kc + 8]) =
            *reinterpret_cast<bf16x8*>(&tmp[8]);
    }
}

// ---------------------------------------------------------------------------
// Shared GEMM body: C[128x128] tile of A[4096][1024] @ Bt[n][k].
// 2-phase dbuf prefetch + XOR-swizzled LDS (pre-swizzled global source).
// ---------------------------------------------------------------------------
template <typename Epi>
__device__ __forceinline__ void gemm128_body(
    const ushortT* __restrict__ A, const ushortT* __restrict__ Bt,
    int rowBase, int colBase, ushortT* As, ushortT* Bs, Epi&& epi) {
    const int tid = threadIdx.x, wid = tid >> 6, lane = tid & 63;
    const int hi = lane >> 4, lo = lane & 15;
    const int wr = wid >> 1, wc = wid & 1;
    const int r8 = lane >> 3, jc = lane & 7;

    const f32x4 z4 = {0.f, 0.f, 0.f, 0.f};
    f32x4 acc[4][4];
    #pragma unroll
    for (int mi = 0; mi < 4; ++mi)
        #pragma unroll
        for (int ni = 0; ni < 4; ++ni) acc[mi][ni] = z4;

    auto STAGE = [&](int buf, int k0) {
        #pragma unroll
        for (int i = 0; i < 4; ++i) {
            const int chunk = wid * 4 + i;                 // wave-uniform
            const int row = chunk * 8 + r8;
            const int c8 = 8 * (jc ^ r8);
            gload_lds16(&A [(size_t)(rowBase + row) * kHID + k0 + c8], &As[buf * 8192 + chunk * 512]);
            gload_lds16(&Bt[(size_t)(colBase + row) * kHID + k0 + c8], &Bs[buf * 8192 + chunk * 512]);
        }
    };

    STAGE(0, 0);
    __syncthreads();
    int cur = 0;

    for (int k0 = 0; k0 < kHID; k0 += 64) {
        if (k0 + 64 < kHID) STAGE(cur ^ 1, k0 + 64);   // async prefetch

        __builtin_amdgcn_s_setprio(1);
        #pragma unroll
        for (int ks = 0; ks < 2; ++ks) {
            bf16x8 af[4], bfr[4];
            #pragma unroll
            for (int mi = 0; mi < 4; ++mi) {
                const int row = 64 * wr + 16 * mi + lo;
                af[mi] = *reinterpret_cast<const bf16x8*>(
                    &As[cur * 8192 + row * 64 + 8 * ((4 * ks + hi) ^ (row & 7))]);
            }
            #pragma unroll
            for (int ni = 0; ni < 4; ++ni) {
                const int row = 64 * wc + 16 * ni + lo;
                bfr[ni] = *reinterpret_cast<const bf16x8*>(
                    &Bs[cur * 8192 + row * 64 + 8 * ((4 * ks + hi) ^ (row & 7))]);
            }
            #pragma unroll
            for (int mi = 0; mi < 4; ++mi)
                #pragma unroll
                for (int ni = 0; ni < 4; ++ni)
                    acc[mi][ni] = MFMA(af[mi], bfr[ni], acc[mi][ni]);
        }
        __builtin_amdgcn_s_setprio(0);

        __syncthreads();   // drains prefetch vmcnt + guards buffer swap
        cur ^= 1;
    }

    epi(acc, wr, wc, hi, lo);
}

// ---------------------------------------------------------------------------
// QKV GEMM: xb @ W (as Wt[n][k]) + bias -> bf16. Q scaled; V transposed [B,H,D,S].
// ---------------------------------------------------------------------------
__global__ __launch_bounds__(256, 2) void qkv_mfma_gemm(
    const ushortT* __restrict__ A, const ushortT* __restrict__ WtAll,
    const float* __restrict__ bq, const float* __restrict__ bk, const float* __restrict__ bv,
    ushortT* __restrict__ qkvb) {
    __shared__ ushortT As[2 * 8192];
    __shared__ ushortT Bs[2 * 8192];

    const int z = blockIdx.z;
    const ushortT* Bt = WtAll + (size_t)z * kHID * kHID;
    const float* bias = (z == 0) ? bq : (z == 1) ? bk : bv;
    ushortT* out = qkvb + (size_t)z * 2 * kNH * kSEQ * kHD;
    const float scale = (z == 0) ? kQScale : 1.0f;
    const int rowBase = blockIdx.y * 128, colBase = blockIdx.x * 128;

    gemm128_body(A, Bt, rowBase, colBase, As, Bs,
        [&](f32x4 (&acc)[4][4], int wr, int wc, int hi, int lo) {
            #pragma unroll
            for (int ni = 0; ni < 4; ++ni) {
                const int col = colBase + 64 * wc + 16 * ni + lo;
                const float bcol = bias[col];
                const int h = col >> 6, d = col & 63;
                #pragma unroll
                for (int mi = 0; mi < 4; ++mi)
                    #pragma unroll
                    for (int r = 0; r < 4; ++r) {
                        const int m = rowBase + 64 * wr + 16 * mi + 4 * hi + r;
                        const int b = m >> 11, s = m & (kSEQ - 1);
                        const ushortT val = f2bf((acc[mi][ni][r] + bcol) * scale);
                        if (z == 2)  // V transposed: [B,H,D,S]
                            out[(((size_t)b * kNH + h) * kHD + d) * kSEQ + s] = val;
                        else         // Q,K: [B,H,S,D]
                            out[(((size_t)b * kNH + h) * kSEQ + s) * kHD + d] = val;
                    }
            }
        });
}

// ---------------------------------------------------------------------------
// Output GEMM: attnb bf16 @ Wo (as Wt) + bo -> fp32 d_out.
// ---------------------------------------------------------------------------
__global__ __launch_bounds__(256, 2) void out_mfma_gemm(
    const ushortT* __restrict__ A, const ushortT* __restrict__ Bt,
    const float* __restrict__ bias, float* __restrict__ out) {
    __shared__ ushortT As[2 * 8192];
    __shared__ ushortT Bs[2 * 8192];

    const int rowBase = blockIdx.y * 128, colBase = blockIdx.x * 128;

    gemm128_body(A, Bt, rowBase, colBase, As, Bs,
        [&](f32x4 (&acc)[4][4], int wr, int wc, int hi, int lo) {
            #pragma unroll
            for (int ni = 0; ni < 4; ++ni) {
                const int col = colBase + 64 * wc + 16 * ni + lo;
                const float bcol = bias[col];
                #pragma unroll
                for (int mi = 0; mi < 4; ++mi)
                    #pragma unroll
                    for (int r = 0; r < 4; ++r) {
                        const int m = rowBase + 64 * wr + 16 * mi + 4 * hi + r;
                        out[(size_t)m * kHID + col] = acc[mi][ni][r] + bcol;
                    }
            }
        });
}

// ---------------------------------------------------------------------------
// MFMA flash attention v10 (kv-slab split). Block = (head, 64 q-rows, b),
// 4 waves; wave w owns kv slab [16w,16w+16) of EVERY tile, covers all 64 q.
// Tiles processed in pairs: QK+exp per tile, PV (K=32) per pair using
// composite k = 8hi + (e&3) + 4*(e>>2) -> pair P packs straight into the
// verified A-fragment. V 3-buffered; K 2-buffered. Partial (acc,l) merged
// across waves by addition (no-max softmax). Swizzle s(row)=(row&3)|(((row>>3)&1)<<2).
// ---------------------------------------------------------------------------
__global__ __launch_bounds__(256, 2) void flash_mfma_kernel(
    const ushortT* __restrict__ Qb, const ushortT* __restrict__ Kb,
    const ushortT* __restrict__ Vtg, ushortT* __restrict__ Ob) {
    __shared__ ushortT Ks[2][64 * 64];
    __shared__ ushortT Vs[3][64 * 64];

    const int tid = threadIdx.x, wid = tid >> 6, lane = tid & 63;
    const int hi = lane >> 4, lo = lane & 15;
    const int h = blockIdx.x;                  // head (XCD-pinned: id%8 == h%8)
    const int q0 = blockIdx.y * 64;
    const size_t headBase = ((size_t)blockIdx.z * kNH + h) * (size_t)(kSEQ * kHD);
    const ushortT* Kg = Kb + headBase;    // [kv][64]
    const ushortT* Vg = Vtg + headBase;   // [d][2048] (pre-transposed)

    // Q fragments (B-operand): qf[qb][c] = Q[q = q0+16qb+lo][d = 32c+8hi+e]
    bf16x8 qf[4][2];
    #pragma unroll
    for (int qb = 0; qb < 4; ++qb)
        #pragma unroll
        for (int c = 0; c < 2; ++c)
            qf[qb][c] = *reinterpret_cast<const bf16x8*>(
                &Qb[headBase + (size_t)(q0 + 16 * qb + lo) * kHD + 32 * c + 8 * hi]);

    const f32x4 z4 = {0.f, 0.f, 0.f, 0.f};
    f32x4 acc[4][4];   // [qb][n] partial O over this wave's kv slabs
    #pragma unroll
    for (int qb = 0; qb < 4; ++qb)
        #pragma unroll
        for (int n = 0; n < 4; ++n) acc[qb][n] = z4;
    float l_[4] = {0.f, 0.f, 0.f, 0.f};   // per-lane partial row sum, q = 16qb+lo

    const int r8 = lane >> 3, jc = lane & 7;  // staging: row-within-8, 16B chunk

    // LDS read addressing (loop-invariant). s(row) = (row&3)|(((row>>3)&1)<<2);
    // K A-frag rows = 16*wid+lo; V^T rows = 16n+lo -> same s expression.
    const int sRow = (lo & 3) | (((lo >> 3) & 1) << 2);
    const int krow64 = (16 * wid + lo) * 64;
    const int kx0 = (8 * hi) ^ (sRow << 3);
    const int kx1 = (32 + 8 * hi) ^ (sRow << 3);
    const int vxc = (16 * wid + 4 * hi) ^ (sRow << 3);   // b64 col (bits 0-2 kept)

    union PU { unsigned u[4]; bf16x8 v; };
    union VU { bf16x4 h[2]; bf16x8 v; };
    PU pa[4];

    // Cooperative stage of one kv64 tile (K -> Ks[kbuf], V^T -> Vs[vbuf]);
    // linear LDS dest, source column pre-XOR'd by s(row).  (v9-proven.)
    auto STAGE = [&](int kbuf, int vbuf, int kv0) {
        #pragma unroll
        for (int i = 0; i < 2; ++i) {
            const int rowBase = (i * 4 + wid) * 8;            // wave-uniform
            const int row = rowBase + r8;
            const int s8 = (r8 & 3) | ((wid & 1) << 2);       // s(row)
            gload_lds16(&Kg[(size_t)(kv0 + row) * kHD + 8 * (jc ^ s8)], &Ks[kbuf][rowBase * 64]);
            gload_lds16(&Vg[(size_t)row * kSEQ + kv0 + 8 * (jc ^ s8)], &Vs[vbuf][rowBase * 64]);
        }
    };

    STAGE(0, 0, 0);
    __syncthreads();

    for (int i = 0; i < kSEQ / 128; ++i) {      // 16 tile-pairs
        const int t0 = 2 * i, t1 = 2 * i + 1;

        // ================= even tile: prefetch t0+1, QK + exp =================
        STAGE((t0 + 1) & 1, (t0 + 1) % 3, (t0 + 1) * 64);   // t0+1 <= 31 always
        {
            const ushortT* kbse = &Ks[t0 & 1][0];
            const bf16x8 kf0 = *reinterpret_cast<const bf16x8*>(&kbse[krow64 + kx0]);
            const bf16x8 kf1 = *reinterpret_cast<const bf16x8*>(&kbse[krow64 + kx1]);
            f32x4 sc[4];
            __builtin_amdgcn_s_setprio(1);
            #pragma unroll
            for (int qb = 0; qb < 4; ++qb)
                sc[qb] = MFMA(kf1, qf[qb][1], MFMA(kf0, qf[qb][0], z4));
            __builtin_amdgcn_s_setprio(0);
            #pragma unroll
            for (int qb = 0; qb < 4; ++qb) {
                const float p0 = exp2f(sc[qb][0]), p1 = exp2f(sc[qb][1]);
                const float p2 = exp2f(sc[qb][2]), p3 = exp2f(sc[qb][3]);
                l_[qb] += (p0 + p1) + (p2 + p3);
                pa[qb].u[0] = cvt_pk_bf16(p0, p1);
                pa[qb].u[1] = cvt_pk_bf16(p2, p3);
            }
        }
        __syncthreads();   // t0+1 staged; Ks[t0&1] free to overwrite next

        // ========== odd tile: prefetch t1+1, QK + exp, PV over the pair ==========
        if (t1 + 1 < kSEQ / 64) STAGE((t1 + 1) & 1, (t1 + 1) % 3, (t1 + 1) * 64);
        {
            const ushortT* kbso = &Ks[t1 & 1][0];
            const bf16x8 kf0 = *reinterpret_cast<const bf16x8*>(&kbso[krow64 + kx0]);
            const bf16x8 kf1 = *reinterpret_cast<const bf16x8*>(&kbso[krow64 + kx1]);
            f32x4 sc[4];
            __builtin_amdgcn_s_setprio(1);
            #pragma unroll
            for (int qb = 0; qb < 4; ++qb)
                sc[qb] = MFMA(kf1, qf[qb][1], MFMA(kf0, qf[qb][0], z4));
            __builtin_amdgcn_s_setprio(0);
            #pragma unroll
            for (int qb = 0; qb < 4; ++qb) {
                const float p0 = exp2f(sc[qb][0]), p1 = exp2f(sc[qb][1]);
                const float p2 = exp2f(sc[qb][2]), p3 = exp2f(sc[qb][3]);
                l_[qb] += (p0 + p1) + (p2 + p3);
                pa[qb].u[2] = cvt_pk_bf16(p0, p1);
                pa[qb].u[3] = cvt_pk_bf16(p2, p3);
            }
        }
        {   // PV (16 MFMA, K=32 over the pair; composite k = 8hi+(e&3)+4(e>>2))
            const ushortT* ve = &Vs[t0 % 3][0];
            const ushortT* vo = &Vs[t1 % 3][0];
            __builtin_amdgcn_s_setprio(1);
            #pragma unroll
            for (int n = 0; n < 4; ++n) {
                const int off = (16 * n + lo) * 64 + vxc;
                VU vu;
                vu.h[0] = *reinterpret_cast<const bf16x4*>(&ve[off]);   // e=0..3 (tile t0)
                vu.h[1] = *reinterpret_cast<const bf16x4*>(&vo[off]);   // e=4..7 (tile t1)
                #pragma unroll
                for (int qb = 0; qb < 4; ++qb)
                    acc[qb][n] = MFMA(pa[qb].v, vu.v, acc[qb][n]);
            }
            __builtin_amdgcn_s_setprio(0);
        }
        __syncthreads();   // drains prefetch vmcnt + guards buffer rotation
    }

    // ================= cross-wave merge (simple add) + epilogue =================
    float* MK = reinterpret_cast<float*>(&Ks[0][0]);   // 4096 f32 (16 KB)
    float* ML = reinterpret_cast<float*>(&Vs[0][0]);   // 64 f32

    #pragma unroll
    for (int qb = 0; qb < 4; ++qb) {
        // reduce l over hi (lanes 16/32 apart share q=16qb+lo)
        float lq = l_[qb];
        lq += __shfl_xor(lq, 16);
        lq += __shfl_xor(lq, 32);

        if (wid != qb) {   // non-reducers publish partials
            #pragma unroll
            for (int n = 0; n < 4; ++n)
                *reinterpret_cast<f32x4*>(&MK[wid * 1024 + n * 256 + lane * 4]) = acc[qb][n];
            if (hi == 0) ML[wid * 16 + lo] = lq;
        }
        __syncthreads();
        if (wid == qb) {   // wave qb reduces q-block qb
            float lt = lq;
            #pragma unroll
            for (int w = 0; w < 4; ++w)
                if (w != qb) lt += ML[w * 16 + lo];
            f32x4 tot[4];
            #pragma unroll
            for (int n = 0; n < 4; ++n) tot[n] = acc[qb][n];
            #pragma unroll
            for (int w = 0; w < 4; ++w) {
                if (w == qb) continue;
                #pragma unroll
                for (int n = 0; n < 4; ++n)
                    tot[n] += *reinterpret_cast<const f32x4*>(&MK[w * 1024 + n * 256 + lane * 4]);
            }
            #pragma unroll
            for (int r = 0; r < 4; ++r) {
                const float inv = 1.0f / __shfl(lt, 4 * hi + r);
                const int s = q0 + 16 * qb + 4 * hi + r;
                const size_t base = ((size_t)blockIdx.z * kSEQ + s) * kHID + (size_t)h * kHD;
                #pragma unroll
                for (int n = 0; n < 4; ++n)
                    Ob[base + 16 * n + lo] = f2bf(tot[n][r] * inv);
            }
        }
        __syncthreads();   // LDS reused next round
    }
}

}  // namespace

extern "C" void kernel_launch(void* const* d_in, const int* in_sizes, int n_in,
                              void* d_out, int out_size, void* d_ws, size_t ws_size,
                              hipStream_t stream) {
    (void)in_sizes; (void)n_in; (void)out_size;
    const float* x  = (const float*)d_in[0];
    const float* Wq = (const float*)d_in[1];
    const float* bq = (const float*)d_in[2];
    const float* Wk = (const float*)d_in[3];
    const float* bk = (const float*)d_in[4];
    const float* Wv = (const float*)d_in[5];
    const float* bv = (const float*)d_in[6];
    const float* Wo = (const float*)d_in[7];
    const float* bo = (const float*)d_in[8];

    constexpr size_t kXE = (size_t)2 * kSEQ * kHID;   // 4 Mi elems
    constexpr size_t kWE = (size_t)kHID * kHID;       // 1 Mi elems
    const size_t needed = (kXE + 4 * kWE + 3 * kXE + kXE) * sizeof(ushortT);
    if (ws_size < needed) return;

    ushortT* xb    = (ushortT*)d_ws;
    ushortT* WtAll = xb + kXE;
    ushortT* qkvb  = WtAll + 4 * kWE;
    ushortT* attnb = qkvb + 3 * kXE;

    const ushortT* qb  = qkvb;            // [B,H,S,D], pre-scaled by 0.125*log2e
    const ushortT* kb  = qkvb + kXE;      // [B,H,S,D]
    const ushortT* vtb = qkvb + 2 * kXE;  // [B,H,D,S]  (transposed)

    cvtx_kernel<<<dim3((unsigned)(kXE / (256 * 4))), 256, 0, stream>>>(x, xb);
    transw_kernel<<<dim3(16, 16, 4), 256, 0, stream>>>(Wq, Wk, Wv, Wo, WtAll);

    qkv_mfma_gemm<<<dim3(8, 32, 3), 256, 0, stream>>>(xb, WtAll, bq, bk, bv, qkvb);

    // blockIdx.x = head: linear id % 8 == head % 8 -> head pinned to one XCD.
    flash_mfma_kernel<<<dim3(kNH, kSEQ / 64, 2), 256, 0, stream>>>(qb, kb, vtb, attnb);

    out_mfma_gemm<<<dim3(8, 32), 256, 0, stream>>>(attnb, WtAll + 3 * kWE, bo, (float*)d_out);
}

// Round 11
// 135.367 us; speedup vs baseline: 1.0926x; 1.0926x over previous
//
#include <hip/hip_runtime.h>
#include <math.h>

// bf16-MFMA MHA v11 = v9 + T4 counted-vmcnt pipelining (flash + both GEMMs).
// __syncthreads (vmcnt(0)-drain) replaced by: counted s_waitcnt vmcnt(N)
// (retires exactly the CURRENT tile's loads; prefetch stays in flight) +
// raw s_barrier pair {data-ready, compute-done}. m218: counted-vs-drain was
// +38-73% on the GEMM 8-phase; m135: vmcnt retires in issue order.
// v10's slab split reverted (3rd failed TLP-trade; 16q/wave 4/SIMD is the
// proven operating point). Head-pinned flash grid (v8: FETCH 69.7->12.4 MB).
// MFMA 16x16x32 bf16 layouts (HW-verified, learn_hip m89/m92):
//   A frag: lane holds A[l&15][8*(l>>4)+e], e=0..7 (k-contiguous bf16x8)
//   B frag: lane holds B[8*(l>>4)+e][l&15]
//   C/D:    lane reg r -> C[(l>>4)*4 + r][l&15]

namespace {

constexpr int kHID = 1024;
constexpr int kNH  = 16;
constexpr int kHD  = 64;
constexpr int kSEQ = 2048;

// 1/sqrt(64) * log2(e): scores in log2 domain -> raw exp2f softmax.
constexpr float kQScale = 0.125f * 1.4426950408889634f;

typedef unsigned short ushortT;
typedef __attribute__((ext_vector_type(8))) short   bf16x8;
typedef __attribute__((ext_vector_type(4))) float   f32x4;
typedef __attribute__((ext_vector_type(4))) unsigned short u16x4;

#define MFMA(a, b, c) __builtin_amdgcn_mfma_f32_16x16x32_bf16((a), (b), (c), 0, 0, 0)
#define SBAR() __builtin_amdgcn_s_barrier()
#define WAITV0() asm volatile("s_waitcnt vmcnt(0)" ::: "memory")
#define WAITV4() asm volatile("s_waitcnt vmcnt(4)" ::: "memory")
#define WAITV8() asm volatile("s_waitcnt vmcnt(8)" ::: "memory")

typedef const __attribute__((address_space(1))) void GVoid;
typedef __attribute__((address_space(3))) void SVoid;

__device__ __forceinline__ void gload_lds16(const ushortT* g, ushortT* l) {
    __builtin_amdgcn_global_load_lds((GVoid*)g, (SVoid*)l, 16, 0, 0);
}

__device__ __forceinline__ ushortT f2bf(float f) {
    unsigned u = __builtin_bit_cast(unsigned, f);
    u += 0x7fffu + ((u >> 16) & 1u);
    return (ushortT)(u >> 16);
}

__device__ __forceinline__ unsigned cvt_pk_bf16(float a, float b) {
    unsigned r;
    asm("v_cvt_pk_bf16_f32 %0, %1, %2" : "=v"(r) : "v"(a), "v"(b));
    return r;  // low half = bf16(a), high half = bf16(b)
}

__device__ __forceinline__ float4 ld4f(const float* p) { return *reinterpret_cast<const float4*>(p); }

// ---------------------------------------------------------------------------
// x fp32 -> bf16
// ---------------------------------------------------------------------------
__global__ __launch_bounds__(256) void cvtx_kernel(const float* __restrict__ x,
                                                   ushortT* __restrict__ xb) {
    const size_t i = ((size_t)blockIdx.x * 256 + threadIdx.x) * 4;
    const float4 f = ld4f(&x[i]);
    u16x4 o = { f2bf(f.x), f2bf(f.y), f2bf(f.z), f2bf(f.w) };
    *reinterpret_cast<u16x4*>(&xb[i]) = o;
}

// ---------------------------------------------------------------------------
// W[k][n] fp32 -> Wt[n][k] bf16, 64x64 tiles via LDS. z selects matrix.
// ---------------------------------------------------------------------------
__global__ __launch_bounds__(256) void transw_kernel(
    const float* __restrict__ W0, const float* __restrict__ W1,
    const float* __restrict__ W2, const float* __restrict__ W3,
    ushortT* __restrict__ WtAll) {
    __shared__ ushortT T[64 * 72];
    const float* W = (blockIdx.z == 0) ? W0 : (blockIdx.z == 1) ? W1 : (blockIdx.z == 2) ? W2 : W3;
    ushortT* Wt = WtAll + (size_t)blockIdx.z * kHID * kHID;
    const int kb = blockIdx.y * 64, nb = blockIdx.x * 64;
    const int tid = threadIdx.x;
    {
        const int kr = tid >> 2, nc = (tid & 3) * 16;
        #pragma unroll
        for (int i = 0; i < 16; i += 4) {
            const float4 f = ld4f(&W[(size_t)(kb + kr) * kHID + nb + nc + i]);
            T[kr * 72 + nc + i + 0] = f2bf(f.x);
            T[kr * 72 + nc + i + 1] = f2bf(f.y);
            T[kr * 72 + nc + i + 2] = f2bf(f.z);
            T[kr * 72 + nc + i + 3] = f2bf(f.w);
        }
    }
    __syncthreads();
    {
        const int nr = tid >> 2, kc = (tid & 3) * 16;
        ushortT tmp[16];
        #pragma unroll
        for (int i = 0; i < 16; ++i) tmp[i] = T[(kc + i) * 72 + nr];
        *reinterpret_cast<bf16x8*>(&Wt[(size_t)(nb + nr) * kHID + kb + kc]) =
            *reinterpret_cast<bf16x8*>(&tmp[0]);
        *reinterpret_cast<bf16x8*>(&Wt[(size_t)(nb + nr) * kHID + kb + kc + 8]) =
            *reinterpret_cast<bf16x8*>(&tmp[8]);
    }
}

// ---------------------------------------------------------------------------
// Shared GEMM body: C[128x128] tile of A[4096][1024] @ Bt[n][k].
// Counted-vmcnt pipeline: STAGE(next) -> vmcnt(8) retires current tile's 8
// loads (in-order, m135) -> s_barrier (data ready) -> MFMA -> s_barrier
// (compute done; guards next STAGE's overwrite of buf k-1).
// XOR-swizzled LDS via pre-swizzled global source (rule #21).
// ---------------------------------------------------------------------------
template <typename Epi>
__device__ __forceinline__ void gemm128_body(
    const ushortT* __restrict__ A, const ushortT* __restrict__ Bt,
    int rowBase, int colBase, ushortT* As, ushortT* Bs, Epi&& epi) {
    const int tid = threadIdx.x, wid = tid >> 6, lane = tid & 63;
    const int hi = lane >> 4, lo = lane & 15;
    const int wr = wid >> 1, wc = wid & 1;
    const int r8 = lane >> 3, jc = lane & 7;

    const f32x4 z4 = {0.f, 0.f, 0.f, 0.f};
    f32x4 acc[4][4];
    #pragma unroll
    for (int mi = 0; mi < 4; ++mi)
        #pragma unroll
        for (int ni = 0; ni < 4; ++ni) acc[mi][ni] = z4;

    auto STAGE = [&](int buf, int k0) {
        #pragma unroll
        for (int i = 0; i < 4; ++i) {
            const int chunk = wid * 4 + i;                 // wave-uniform
            const int row = chunk * 8 + r8;
            const int c8 = 8 * (jc ^ r8);
            gload_lds16(&A [(size_t)(rowBase + row) * kHID + k0 + c8], &As[buf * 8192 + chunk * 512]);
            gload_lds16(&Bt[(size_t)(colBase + row) * kHID + k0 + c8], &Bs[buf * 8192 + chunk * 512]);
        }
    };

    STAGE(0, 0);

    for (int t = 0; t < kHID / 64; ++t) {
        const int cur = t & 1;
        if (t + 1 < kHID / 64) {
            STAGE(cur ^ 1, (t + 1) * 64);   // prefetch stays in flight across barriers
            WAITV8();                        // retire exactly tile t's 8 loads
        } else {
            WAITV0();
        }
        SBAR();                              // tile t visible to all waves

        __builtin_amdgcn_s_setprio(1);
        #pragma unroll
        for (int ks = 0; ks < 2; ++ks) {
            bf16x8 af[4], bfr[4];
            #pragma unroll
            for (int mi = 0; mi < 4; ++mi) {
                const int row = 64 * wr + 16 * mi + lo;
                af[mi] = *reinterpret_cast<const bf16x8*>(
                    &As[cur * 8192 + row * 64 + 8 * ((4 * ks + hi) ^ (row & 7))]);
            }
            #pragma unroll
            for (int ni = 0; ni < 4; ++ni) {
                const int row = 64 * wc + 16 * ni + lo;
                bfr[ni] = *reinterpret_cast<const bf16x8*>(
                    &Bs[cur * 8192 + row * 64 + 8 * ((4 * ks + hi) ^ (row & 7))]);
            }
            #pragma unroll
            for (int mi = 0; mi < 4; ++mi)
                #pragma unroll
                for (int ni = 0; ni < 4; ++ni)
                    acc[mi][ni] = MFMA(af[mi], bfr[ni], acc[mi][ni]);
        }
        __builtin_amdgcn_s_setprio(0);

        SBAR();                              // all waves done reading tile t
    }

    epi(acc, wr, wc, hi, lo);
}

// ---------------------------------------------------------------------------
// QKV GEMM: xb @ W (as Wt[n][k]) + bias -> bf16. Q scaled; V transposed [B,H,D,S].
// ---------------------------------------------------------------------------
__global__ __launch_bounds__(256, 2) void qkv_mfma_gemm(
    const ushortT* __restrict__ A, const ushortT* __restrict__ WtAll,
    const float* __restrict__ bq, const float* __restrict__ bk, const float* __restrict__ bv,
    ushortT* __restrict__ qkvb) {
    __shared__ ushortT As[2 * 8192];
    __shared__ ushortT Bs[2 * 8192];

    const int z = blockIdx.z;
    const ushortT* Bt = WtAll + (size_t)z * kHID * kHID;
    const float* bias = (z == 0) ? bq : (z == 1) ? bk : bv;
    ushortT* out = qkvb + (size_t)z * 2 * kNH * kSEQ * kHD;
    const float scale = (z == 0) ? kQScale : 1.0f;
    const int rowBase = blockIdx.y * 128, colBase = blockIdx.x * 128;

    gemm128_body(A, Bt, rowBase, colBase, As, Bs,
        [&](f32x4 (&acc)[4][4], int wr, int wc, int hi, int lo) {
            #pragma unroll
            for (int ni = 0; ni < 4; ++ni) {
                const int col = colBase + 64 * wc + 16 * ni + lo;
                const float bcol = bias[col];
                const int h = col >> 6, d = col & 63;
                #pragma unroll
                for (int mi = 0; mi < 4; ++mi)
                    #pragma unroll
                    for (int r = 0; r < 4; ++r) {
                        const int m = rowBase + 64 * wr + 16 * mi + 4 * hi + r;
                        const int b = m >> 11, s = m & (kSEQ - 1);
                        const ushortT val = f2bf((acc[mi][ni][r] + bcol) * scale);
                        if (z == 2)  // V transposed: [B,H,D,S]
                            out[(((size_t)b * kNH + h) * kHD + d) * kSEQ + s] = val;
                        else         // Q,K: [B,H,S,D]
                            out[(((size_t)b * kNH + h) * kSEQ + s) * kHD + d] = val;
                    }
            }
        });
}

// ---------------------------------------------------------------------------
// Output GEMM: attnb bf16 @ Wo (as Wt) + bo -> fp32 d_out.
// ---------------------------------------------------------------------------
__global__ __launch_bounds__(256, 2) void out_mfma_gemm(
    const ushortT* __restrict__ A, const ushortT* __restrict__ Bt,
    const float* __restrict__ bias, float* __restrict__ out) {
    __shared__ ushortT As[2 * 8192];
    __shared__ ushortT Bs[2 * 8192];

    const int rowBase = blockIdx.y * 128, colBase = blockIdx.x * 128;

    gemm128_body(A, Bt, rowBase, colBase, As, Bs,
        [&](f32x4 (&acc)[4][4], int wr, int wc, int hi, int lo) {
            #pragma unroll
            for (int ni = 0; ni < 4; ++ni) {
                const int col = colBase + 64 * wc + 16 * ni + lo;
                const float bcol = bias[col];
                #pragma unroll
                for (int mi = 0; mi < 4; ++mi)
                    #pragma unroll
                    for (int r = 0; r < 4; ++r) {
                        const int m = rowBase + 64 * wr + 16 * mi + 4 * hi + r;
                        out[(size_t)m * kHID + col] = acc[mi][ni][r] + bcol;
                    }
            }
        });
}

// ---------------------------------------------------------------------------
// MFMA flash attention v11 (= v9 + counted-vmcnt pipeline). Block = (head,
// 64 q-rows, b); head-pinned grid. 4 waves x 16 q-rows, swapped QK^T, no
// max-tracking, ones-MFMA row sums. K/V^T double-buffered via global_load_lds
// w=16 with pre-swizzled source; swizzle s(row) = (row&3)|(((row>>3)&1)<<2).
// Pipeline: STAGE(t+1) -> vmcnt(4) -> s_barrier -> compute(t) -> s_barrier.
// ---------------------------------------------------------------------------
__global__ __launch_bounds__(256, 4) void flash_mfma_kernel(
    const ushortT* __restrict__ Qb, const ushortT* __restrict__ Kb,
    const ushortT* __restrict__ Vtg, ushortT* __restrict__ Ob) {
    __shared__ ushortT Ks[2][64 * 64];
    __shared__ ushortT Vs[2][64 * 64];

    const int tid = threadIdx.x, wid = tid >> 6, lane = tid & 63;
    const int hi = lane >> 4, lo = lane & 15;
    const int h = blockIdx.x;                  // head (XCD-pinned: id%8 == h%8)
    const int q0 = blockIdx.y * 64;
    const size_t headBase = ((size_t)blockIdx.z * kNH + h) * (size_t)(kSEQ * kHD);
    const ushortT* Kg = Kb + headBase;    // [kv][64]
    const ushortT* Vg = Vtg + headBase;   // [d][2048] (pre-transposed)

    // Q fragments (B-operand of swapped QK^T): lane holds Q[q=lo][d=32c+8hi+e]
    bf16x8 qf[2];
    #pragma unroll
    for (int c = 0; c < 2; ++c)
        qf[c] = *reinterpret_cast<const bf16x8*>(
            &Qb[headBase + (size_t)(q0 + 16 * wid + lo) * kHD + 32 * c + 8 * hi]);

    // ones B-fragment for row-sum MFMA (bf16 1.0 = 0x3F80)
    const short one = (short)0x3F80;
    const bf16x8 ones = {one, one, one, one, one, one, one, one};

    const f32x4 z4 = {0.f, 0.f, 0.f, 0.f};
    f32x4 acc[4] = {z4, z4, z4, z4};
    f32x4 accL = z4;   // accL[r] = running row-sum for q = 4hi+r (same idx as acc)

    const int r8 = lane >> 3, jc = lane & 7;  // staging: row-within-8, 16B chunk

    // K-fragment addressing (row-permuted): kappa = 8*(lo>>2)+(lo&3)+4*(f&1)+32*(f>>1)
    const int kap0 = 8 * (lo >> 2) + (lo & 3);
    const int sk = (lo & 3) | (((lo >> 2) & 1) << 2);        // s(kappa), f-invariant
    const int kx0 = (8 * hi) ^ (sk << 3);                     // d-chunk m=0
    const int kx1 = (32 + 8 * hi) ^ (sk << 3);                // d-chunk m=1
    const int sv = (lo & 3) | (((lo >> 3) & 1) << 2);         // s(vrow), n-invariant

    // Stage one 64-wide kv tile of K and V^T: linear LDS dest, source column
    // pre-XOR'd by s(row) so swizzled reads see G[row][x] at LDS[row][x^(s<<3)].
    auto STAGE = [&](int buf, int kv0) {
        #pragma unroll
        for (int i = 0; i < 2; ++i) {
            const int rowBase = (i * 4 + wid) * 8;            // wave-uniform
            const int row = rowBase + r8;
            const int s8 = (r8 & 3) | ((wid & 1) << 2);       // s(row)
            gload_lds16(&Kg[(size_t)(kv0 + row) * kHD + 8 * (jc ^ s8)], &Ks[buf][rowBase * 64]);
            gload_lds16(&Vg[(size_t)row * kSEQ + kv0 + 8 * (jc ^ s8)], &Vs[buf][rowBase * 64]);
        }
    };

    STAGE(0, 0);

    for (int t = 0; t < kSEQ / 64; ++t) {
        const int cur = t & 1;
        if (t + 1 < kSEQ / 64) {
            STAGE(cur ^ 1, (t + 1) * 64);   // prefetch stays in flight across barriers
            WAITV4();                        // retire exactly tile t's 4 loads
        } else {
            WAITV0();
        }
        SBAR();                              // tile t visible to all waves

        // ---- swapped QK^T (8 MFMA): sc[f] reg r = S[q=lo][kv=8hi+r+4(f&1)+32(f>>1)] ----
        f32x4 sc[4];
        __builtin_amdgcn_s_setprio(1);
        #pragma unroll
        for (int f = 0; f < 4; ++f) {
            const int kap = kap0 + 4 * (f & 1) + 32 * (f >> 1);
            const bf16x8 kf0 = *reinterpret_cast<const bf16x8*>(&Ks[cur][kap * 64 + kx0]);
            const bf16x8 kf1 = *reinterpret_cast<const bf16x8*>(&Ks[cur][kap * 64 + kx1]);
            sc[f] = MFMA(kf1, qf[1], MFMA(kf0, qf[0], z4));
        }
        __builtin_amdgcn_s_setprio(0);

        // ---- softmax without max-tracking: p = exp2(sc) (scores bounded) ----
        float p[4][4];
        #pragma unroll
        for (int f = 0; f < 4; ++f)
            #pragma unroll
            for (int r = 0; r < 4; ++r) p[f][r] = exp2f(sc[f][r]);

        // ---- build PV A-fragments in-register: kv = 32c+8hi+e ----
        union U { unsigned u[4]; bf16x8 v; };
        U pa0, pa1;
        pa0.u[0] = cvt_pk_bf16(p[0][0], p[0][1]);
        pa0.u[1] = cvt_pk_bf16(p[0][2], p[0][3]);
        pa0.u[2] = cvt_pk_bf16(p[1][0], p[1][1]);
        pa0.u[3] = cvt_pk_bf16(p[1][2], p[1][3]);
        pa1.u[0] = cvt_pk_bf16(p[2][0], p[2][1]);
        pa1.u[1] = cvt_pk_bf16(p[2][2], p[2][3]);
        pa1.u[2] = cvt_pk_bf16(p[3][0], p[3][1]);
        pa1.u[3] = cvt_pk_bf16(p[3][2], p[3][3]);

        // ---- PV (8 MFMA) + row-sum (2 ones-MFMA) ----
        __builtin_amdgcn_s_setprio(1);
        accL = MFMA(pa0.v, ones, accL);
        accL = MFMA(pa1.v, ones, accL);
        #pragma unroll
        for (int n = 0; n < 4; ++n) {
            const int vrow = 16 * n + lo;
            const bf16x8 vf0 = *reinterpret_cast<const bf16x8*>(
                &Vs[cur][vrow * 64 + ((8 * hi) ^ (sv << 3))]);
            const bf16x8 vf1 = *reinterpret_cast<const bf16x8*>(
                &Vs[cur][vrow * 64 + ((32 + 8 * hi) ^ (sv << 3))]);
            acc[n] = MFMA(pa0.v, vf0, acc[n]);
            acc[n] = MFMA(pa1.v, vf1, acc[n]);
        }
        __builtin_amdgcn_s_setprio(0);

        SBAR();                              // all waves done reading tile t
    }

    // ---- epilogue: divide by accL (same (hi,r) indexing), write bf16 [B,S,HID] ----
    #pragma unroll
    for (int r = 0; r < 4; ++r) {
        const float inv = 1.0f / accL[r];
        const int s = q0 + 16 * wid + 4 * hi + r;
        const size_t base = ((size_t)blockIdx.z * kSEQ + s) * kHID + (size_t)h * kHD;
        #pragma unroll
        for (int n = 0; n < 4; ++n)
            Ob[base + 16 * n + lo] = f2bf(acc[n][r] * inv);
    }
}

}  // namespace

extern "C" void kernel_launch(void* const* d_in, const int* in_sizes, int n_in,
                              void* d_out, int out_size, void* d_ws, size_t ws_size,
                              hipStream_t stream) {
    (void)in_sizes; (void)n_in; (void)out_size;
    const float* x  = (const float*)d_in[0];
    const float* Wq = (const float*)d_in[1];
    const float* bq = (const float*)d_in[2];
    const float* Wk = (const float*)d_in[3];
    const float* bk = (const float*)d_in[4];
    const float* Wv = (const float*)d_in[5];
    const float* bv = (const float*)d_in[6];
    const float* Wo = (const float*)d_in[7];
    const float* bo = (const float*)d_in[8];

    constexpr size_t kXE = (size_t)2 * kSEQ * kHID;   // 4 Mi elems
    constexpr size_t kWE = (size_t)kHID * kHID;       // 1 Mi elems
    const size_t needed = (kXE + 4 * kWE + 3 * kXE + kXE) * sizeof(ushortT);
    if (ws_size < needed) return;

    ushortT* xb    = (ushortT*)d_ws;
    ushortT* WtAll = xb + kXE;
    ushortT* qkvb  = WtAll + 4 * kWE;
    ushortT* attnb = qkvb + 3 * kXE;

    const ushortT* qb  = qkvb;            // [B,H,S,D], pre-scaled by 0.125*log2e
    const ushortT* kb  = qkvb + kXE;      // [B,H,S,D]
    const ushortT* vtb = qkvb + 2 * kXE;  // [B,H,D,S]  (transposed)

    cvtx_kernel<<<dim3((unsigned)(kXE / (256 * 4))), 256, 0, stream>>>(x, xb);
    transw_kernel<<<dim3(16, 16, 4), 256, 0, stream>>>(Wq, Wk, Wv, Wo, WtAll);

    qkv_mfma_gemm<<<dim3(8, 32, 3), 256, 0, stream>>>(xb, WtAll, bq, bk, bv, qkvb);

    // blockIdx.x = head: linear id % 8 == head % 8 -> head pinned to one XCD.
    flash_mfma_kernel<<<dim3(kNH, kSEQ / 64, 2), 256, 0, stream>>>(qb, kb, vtb, attnb);

    out_mfma_gemm<<<dim3(8, 32), 256, 0, stream>>>(attnb, WtAll + 3 * kWE, bo, (float*)d_out);
}

// Round 12
// 127.008 us; speedup vs baseline: 1.1645x; 1.0658x over previous
//
#include <hip/hip_runtime.h>
#include <math.h>

// bf16-MFMA MHA v12: flash frozen at v11 (LDS-pipe roofline ~82%). GEMM stack
// re-tiled for occupancy: BK=32 (LDS 64->32KB, 2->3 blocks/CU for qkv);
// out-proj 64Mx128N tiles (1->2 blocks/CU); cvtx+transw fused into one launch.
// Swizzle re-derived for 4-chunk rows: chunk ^= row&3 (2-way max = free, m136).
// MFMA 16x16x32 bf16 layouts (HW-verified, learn_hip m89/m92):
//   A frag: lane holds A[l&15][8*(l>>4)+e], e=0..7 (k-contiguous bf16x8)
//   B frag: lane holds B[8*(l>>4)+e][l&15]
//   C/D:    lane reg r -> C[(l>>4)*4 + r][l&15]

namespace {

constexpr int kHID = 1024;
constexpr int kNH  = 16;
constexpr int kHD  = 64;
constexpr int kSEQ = 2048;

// 1/sqrt(64) * log2(e): scores in log2 domain -> raw exp2f softmax.
constexpr float kQScale = 0.125f * 1.4426950408889634f;

typedef unsigned short ushortT;
typedef __attribute__((ext_vector_type(8))) short   bf16x8;
typedef __attribute__((ext_vector_type(4))) float   f32x4;
typedef __attribute__((ext_vector_type(4))) unsigned short u16x4;

#define MFMA(a, b, c) __builtin_amdgcn_mfma_f32_16x16x32_bf16((a), (b), (c), 0, 0, 0)
#define SBAR() __builtin_amdgcn_s_barrier()
#define WAITV0() asm volatile("s_waitcnt vmcnt(0)" ::: "memory")
#define WAITV3() asm volatile("s_waitcnt vmcnt(3)" ::: "memory")
#define WAITV4() asm volatile("s_waitcnt vmcnt(4)" ::: "memory")

typedef const __attribute__((address_space(1))) void GVoid;
typedef __attribute__((address_space(3))) void SVoid;

__device__ __forceinline__ void gload_lds16(const ushortT* g, ushortT* l) {
    __builtin_amdgcn_global_load_lds((GVoid*)g, (SVoid*)l, 16, 0, 0);
}

__device__ __forceinline__ ushortT f2bf(float f) {
    unsigned u = __builtin_bit_cast(unsigned, f);
    u += 0x7fffu + ((u >> 16) & 1u);
    return (ushortT)(u >> 16);
}

__device__ __forceinline__ unsigned cvt_pk_bf16(float a, float b) {
    unsigned r;
    asm("v_cvt_pk_bf16_f32 %0, %1, %2" : "=v"(r) : "v"(a), "v"(b));
    return r;  // low half = bf16(a), high half = bf16(b)
}

__device__ __forceinline__ float4 ld4f(const float* p) { return *reinterpret_cast<const float4*>(p); }

// ---------------------------------------------------------------------------
// Fused prep: blocks [0,4096) convert x fp32->bf16 (1024 elems each);
// blocks [4096,5120) transpose-convert the 4 weight matrices (64x64 tiles).
// ---------------------------------------------------------------------------
__global__ __launch_bounds__(256) void prep_kernel(
    const float* __restrict__ x, ushortT* __restrict__ xb,
    const float* __restrict__ W0, const float* __restrict__ W1,
    const float* __restrict__ W2, const float* __restrict__ W3,
    ushortT* __restrict__ WtAll) {
    __shared__ ushortT T[64 * 72];
    const int bx = blockIdx.x;
    const int tid = threadIdx.x;

    if (bx < 4096) {   // ---- x convert ----
        const size_t i = ((size_t)bx * 256 + tid) * 4;
        const float4 f = ld4f(&x[i]);
        u16x4 o = { f2bf(f.x), f2bf(f.y), f2bf(f.z), f2bf(f.w) };
        *reinterpret_cast<u16x4*>(&xb[i]) = o;
        return;
    }

    // ---- weight transpose: id2 = z*256 + (kb16)*16 + nb16 ----
    const int id2 = bx - 4096;
    const int z = id2 >> 8;
    const float* W = (z == 0) ? W0 : (z == 1) ? W1 : (z == 2) ? W2 : W3;
    ushortT* Wt = WtAll + (size_t)z * kHID * kHID;
    const int kb = ((id2 >> 4) & 15) * 64, nb = (id2 & 15) * 64;
    {
        const int kr = tid >> 2, nc = (tid & 3) * 16;
        #pragma unroll
        for (int i = 0; i < 16; i += 4) {
            const float4 f = ld4f(&W[(size_t)(kb + kr) * kHID + nb + nc + i]);
            T[kr * 72 + nc + i + 0] = f2bf(f.x);
            T[kr * 72 + nc + i + 1] = f2bf(f.y);
            T[kr * 72 + nc + i + 2] = f2bf(f.z);
            T[kr * 72 + nc + i + 3] = f2bf(f.w);
        }
    }
    __syncthreads();
    {
        const int nr = tid >> 2, kc = (tid & 3) * 16;
        ushortT tmp[16];
        #pragma unroll
        for (int i = 0; i < 16; ++i) tmp[i] = T[(kc + i) * 72 + nr];
        *reinterpret_cast<bf16x8*>(&Wt[(size_t)(nb + nr) * kHID + kb + kc]) =
            *reinterpret_cast<bf16x8*>(&tmp[0]);
        *reinterpret_cast<bf16x8*>(&Wt[(size_t)(nb + nr) * kHID + kb + kc + 8]) =
            *reinterpret_cast<bf16x8*>(&tmp[8]);
    }
}

// ---------------------------------------------------------------------------
// QKV GEMM: 128x128 tile, BK=32 (LDS 32KB -> 3 blocks/CU). Counted-vmcnt
// pipeline (v11). Swizzle: LDS[row][chunk] holds G[row][chunk^(row&3)];
// frag read at chunk hi^(row&3) -> banks 2-way max (free).
// Q scaled; V transposed [B,H,D,S].
// ---------------------------------------------------------------------------
__global__ __launch_bounds__(256, 4) void qkv_mfma_gemm(
    const ushortT* __restrict__ A, const ushortT* __restrict__ WtAll,
    const float* __restrict__ bq, const float* __restrict__ bk, const float* __restrict__ bv,
    ushortT* __restrict__ qkvb) {
    __shared__ ushortT As[2 * 4096];
    __shared__ ushortT Bs[2 * 4096];

    const int z = blockIdx.z;
    const ushortT* Bt = WtAll + (size_t)z * kHID * kHID;
    const float* bias = (z == 0) ? bq : (z == 1) ? bk : bv;
    ushortT* out = qkvb + (size_t)z * 2 * kNH * kSEQ * kHD;
    const float scale = (z == 0) ? kQScale : 1.0f;

    const int tid = threadIdx.x, wid = tid >> 6, lane = tid & 63;
    const int hi = lane >> 4, lo = lane & 15;
    const int wr = wid >> 1, wc = wid & 1;
    const int rowBase = blockIdx.y * 128, colBase = blockIdx.x * 128;
    const int sr = lane >> 2, sj = lane & 3;   // staging: 16 rows x 4 chunks per instr

    const f32x4 z4 = {0.f, 0.f, 0.f, 0.f};
    f32x4 acc[4][4];
    #pragma unroll
    for (int mi = 0; mi < 4; ++mi)
        #pragma unroll
        for (int ni = 0; ni < 4; ++ni) acc[mi][ni] = z4;

    // Stage one 128x32 tile pair. Linear LDS dest; source chunk pre-XOR'd by row&3.
    auto STAGE = [&](int buf, int k0) {
        #pragma unroll
        for (int i = 0; i < 2; ++i) {
            const int chunk = wid * 2 + i;                 // wave-uniform
            const int row = chunk * 16 + sr;
            const int c8 = 8 * (sj ^ (sr & 3));            // row&3 == sr&3
            gload_lds16(&A [(size_t)(rowBase + row) * kHID + k0 + c8], &As[buf * 4096 + chunk * 512]);
            gload_lds16(&Bt[(size_t)(colBase + row) * kHID + k0 + c8], &Bs[buf * 4096 + chunk * 512]);
        }
    };

    STAGE(0, 0);

    for (int t = 0; t < kHID / 32; ++t) {
        const int cur = t & 1;
        if (t + 1 < kHID / 32) {
            STAGE(cur ^ 1, (t + 1) * 32);
            WAITV4();                        // retire exactly tile t's 4 loads
        } else {
            WAITV0();
        }
        SBAR();

        __builtin_amdgcn_s_setprio(1);
        bf16x8 af[4], bfr[4];
        #pragma unroll
        for (int mi = 0; mi < 4; ++mi) {
            const int row = 64 * wr + 16 * mi + lo;
            af[mi] = *reinterpret_cast<const bf16x8*>(
                &As[cur * 4096 + row * 32 + 8 * (hi ^ (row & 3))]);
        }
        #pragma unroll
        for (int ni = 0; ni < 4; ++ni) {
            const int row = 64 * wc + 16 * ni + lo;
            bfr[ni] = *reinterpret_cast<const bf16x8*>(
                &Bs[cur * 4096 + row * 32 + 8 * (hi ^ (row & 3))]);
        }
        #pragma unroll
        for (int mi = 0; mi < 4; ++mi)
            #pragma unroll
            for (int ni = 0; ni < 4; ++ni)
                acc[mi][ni] = MFMA(af[mi], bfr[ni], acc[mi][ni]);
        __builtin_amdgcn_s_setprio(0);

        SBAR();
    }

    #pragma unroll
    for (int ni = 0; ni < 4; ++ni) {
        const int col = colBase + 64 * wc + 16 * ni + lo;
        const float bcol = bias[col];
        const int h = col >> 6, d = col & 63;
        #pragma unroll
        for (int mi = 0; mi < 4; ++mi)
            #pragma unroll
            for (int r = 0; r < 4; ++r) {
                const int m = rowBase + 64 * wr + 16 * mi + 4 * hi + r;
                const int b = m >> 11, s = m & (kSEQ - 1);
                const ushortT val = f2bf((acc[mi][ni][r] + bcol) * scale);
                if (z == 2)  // V transposed: [B,H,D,S]
                    out[(((size_t)b * kNH + h) * kHD + d) * kSEQ + s] = val;
                else         // Q,K: [B,H,S,D]
                    out[(((size_t)b * kNH + h) * kSEQ + s) * kHD + d] = val;
            }
    }
}

// ---------------------------------------------------------------------------
// Output GEMM: 64M x 128N tiles, BK=32 -> 512 blocks (2/CU, was 1/CU).
// attnb bf16 @ Wo (as Wt) + bo -> fp32 d_out. Same swizzle/pipeline.
// Waves: wr = wid>>1 over 2 M-halves (32 rows), wc = wid&1 over 2 N-halves (64).
// ---------------------------------------------------------------------------
__global__ __launch_bounds__(256, 2) void out_mfma_gemm(
    const ushortT* __restrict__ A, const ushortT* __restrict__ Bt,
    const float* __restrict__ bias, float* __restrict__ out) {
    __shared__ ushortT As[2 * 2048];
    __shared__ ushortT Bs[2 * 4096];

    const int tid = threadIdx.x, wid = tid >> 6, lane = tid & 63;
    const int hi = lane >> 4, lo = lane & 15;
    const int wr = wid >> 1, wc = wid & 1;
    const int rowBase = blockIdx.y * 64, colBase = blockIdx.x * 128;
    const int sr = lane >> 2, sj = lane & 3;

    const f32x4 z4 = {0.f, 0.f, 0.f, 0.f};
    f32x4 acc[2][4];
    #pragma unroll
    for (int mi = 0; mi < 2; ++mi)
        #pragma unroll
        for (int ni = 0; ni < 4; ++ni) acc[mi][ni] = z4;

    // Stage: A 64x32 (4 instr, 1/wave) + B 128x32 (8 instr, 2/wave) = 3/wave.
    auto STAGE = [&](int buf, int k0) {
        {
            const int chunk = wid;                          // wave-uniform
            const int row = chunk * 16 + sr;
            const int c8 = 8 * (sj ^ (sr & 3));
            gload_lds16(&A[(size_t)(rowBase + row) * kHID + k0 + c8], &As[buf * 2048 + chunk * 512]);
        }
        #pragma unroll
        for (int i = 0; i < 2; ++i) {
            const int chunk = wid * 2 + i;
            const int row = chunk * 16 + sr;
            const int c8 = 8 * (sj ^ (sr & 3));
            gload_lds16(&Bt[(size_t)(colBase + row) * kHID + k0 + c8], &Bs[buf * 4096 + chunk * 512]);
        }
    };

    STAGE(0, 0);

    for (int t = 0; t < kHID / 32; ++t) {
        const int cur = t & 1;
        if (t + 1 < kHID / 32) {
            STAGE(cur ^ 1, (t + 1) * 32);
            WAITV3();                        // retire exactly tile t's 3 loads
        } else {
            WAITV0();
        }
        SBAR();

        __builtin_amdgcn_s_setprio(1);
        bf16x8 af[2], bfr[4];
        #pragma unroll
        for (int mi = 0; mi < 2; ++mi) {
            const int row = 32 * wr + 16 * mi + lo;
            af[mi] = *reinterpret_cast<const bf16x8*>(
                &As[cur * 2048 + row * 32 + 8 * (hi ^ (row & 3))]);
        }
        #pragma unroll
        for (int ni = 0; ni < 4; ++ni) {
            const int row = 64 * wc + 16 * ni + lo;
            bfr[ni] = *reinterpret_cast<const bf16x8*>(
                &Bs[cur * 4096 + row * 32 + 8 * (hi ^ (row & 3))]);
        }
        #pragma unroll
        for (int mi = 0; mi < 2; ++mi)
            #pragma unroll
            for (int ni = 0; ni < 4; ++ni)
                acc[mi][ni] = MFMA(af[mi], bfr[ni], acc[mi][ni]);
        __builtin_amdgcn_s_setprio(0);

        SBAR();
    }

    #pragma unroll
    for (int ni = 0; ni < 4; ++ni) {
        const int col = colBase + 64 * wc + 16 * ni + lo;
        const float bcol = bias[col];
        #pragma unroll
        for (int mi = 0; mi < 2; ++mi)
            #pragma unroll
            for (int r = 0; r < 4; ++r) {
                const int m = rowBase + 32 * wr + 16 * mi + 4 * hi + r;
                out[(size_t)m * kHID + col] = acc[mi][ni][r] + bcol;
            }
    }
}

// ---------------------------------------------------------------------------
// MFMA flash attention (v11, frozen — ~82% of the LDS-pipe roofline).
// Block = (head, 64 q-rows, b); head-pinned grid (id%8 == h%8). 4 waves x 16
// q-rows, swapped QK^T, no max-tracking, ones-MFMA row sums. K/V^T dbuf via
// global_load_lds w=16 pre-swizzled source; s(row) = (row&3)|(((row>>3)&1)<<2).
// Pipeline: STAGE(t+1) -> vmcnt(4) -> s_barrier -> compute(t) -> s_barrier.
// ---------------------------------------------------------------------------
__global__ __launch_bounds__(256, 4) void flash_mfma_kernel(
    const ushortT* __restrict__ Qb, const ushortT* __restrict__ Kb,
    const ushortT* __restrict__ Vtg, ushortT* __restrict__ Ob) {
    __shared__ ushortT Ks[2][64 * 64];
    __shared__ ushortT Vs[2][64 * 64];

    const int tid = threadIdx.x, wid = tid >> 6, lane = tid & 63;
    const int hi = lane >> 4, lo = lane & 15;
    const int h = blockIdx.x;                  // head (XCD-pinned: id%8 == h%8)
    const int q0 = blockIdx.y * 64;
    const size_t headBase = ((size_t)blockIdx.z * kNH + h) * (size_t)(kSEQ * kHD);
    const ushortT* Kg = Kb + headBase;    // [kv][64]
    const ushortT* Vg = Vtg + headBase;   // [d][2048] (pre-transposed)

    bf16x8 qf[2];
    #pragma unroll
    for (int c = 0; c < 2; ++c)
        qf[c] = *reinterpret_cast<const bf16x8*>(
            &Qb[headBase + (size_t)(q0 + 16 * wid + lo) * kHD + 32 * c + 8 * hi]);

    const short one = (short)0x3F80;
    const bf16x8 ones = {one, one, one, one, one, one, one, one};

    const f32x4 z4 = {0.f, 0.f, 0.f, 0.f};
    f32x4 acc[4] = {z4, z4, z4, z4};
    f32x4 accL = z4;

    const int r8 = lane >> 3, jc = lane & 7;

    const int kap0 = 8 * (lo >> 2) + (lo & 3);
    const int sk = (lo & 3) | (((lo >> 2) & 1) << 2);
    const int kx0 = (8 * hi) ^ (sk << 3);
    const int kx1 = (32 + 8 * hi) ^ (sk << 3);
    const int sv = (lo & 3) | (((lo >> 3) & 1) << 2);

    auto STAGE = [&](int buf, int kv0) {
        #pragma unroll
        for (int i = 0; i < 2; ++i) {
            const int rowBase = (i * 4 + wid) * 8;
            const int row = rowBase + r8;
            const int s8 = (r8 & 3) | ((wid & 1) << 2);
            gload_lds16(&Kg[(size_t)(kv0 + row) * kHD + 8 * (jc ^ s8)], &Ks[buf][rowBase * 64]);
            gload_lds16(&Vg[(size_t)row * kSEQ + kv0 + 8 * (jc ^ s8)], &Vs[buf][rowBase * 64]);
        }
    };

    STAGE(0, 0);

    for (int t = 0; t < kSEQ / 64; ++t) {
        const int cur = t & 1;
        if (t + 1 < kSEQ / 64) {
            STAGE(cur ^ 1, (t + 1) * 64);
            WAITV4();
        } else {
            WAITV0();
        }
        SBAR();

        f32x4 sc[4];
        __builtin_amdgcn_s_setprio(1);
        #pragma unroll
        for (int f = 0; f < 4; ++f) {
            const int kap = kap0 + 4 * (f & 1) + 32 * (f >> 1);
            const bf16x8 kf0 = *reinterpret_cast<const bf16x8*>(&Ks[cur][kap * 64 + kx0]);
            const bf16x8 kf1 = *reinterpret_cast<const bf16x8*>(&Ks[cur][kap * 64 + kx1]);
            sc[f] = MFMA(kf1, qf[1], MFMA(kf0, qf[0], z4));
        }
        __builtin_amdgcn_s_setprio(0);

        float p[4][4];
        #pragma unroll
        for (int f = 0; f < 4; ++f)
            #pragma unroll
            for (int r = 0; r < 4; ++r) p[f][r] = exp2f(sc[f][r]);

        union U { unsigned u[4]; bf16x8 v; };
        U pa0, pa1;
        pa0.u[0] = cvt_pk_bf16(p[0][0], p[0][1]);
        pa0.u[1] = cvt_pk_bf16(p[0][2], p[0][3]);
        pa0.u[2] = cvt_pk_bf16(p[1][0], p[1][1]);
        pa0.u[3] = cvt_pk_bf16(p[1][2], p[1][3]);
        pa1.u[0] = cvt_pk_bf16(p[2][0], p[2][1]);
        pa1.u[1] = cvt_pk_bf16(p[2][2], p[2][3]);
        pa1.u[2] = cvt_pk_bf16(p[3][0], p[3][1]);
        pa1.u[3] = cvt_pk_bf16(p[3][2], p[3][3]);

        __builtin_amdgcn_s_setprio(1);
        accL = MFMA(pa0.v, ones, accL);
        accL = MFMA(pa1.v, ones, accL);
        #pragma unroll
        for (int n = 0; n < 4; ++n) {
            const int vrow = 16 * n + lo;
            const bf16x8 vf0 = *reinterpret_cast<const bf16x8*>(
                &Vs[cur][vrow * 64 + ((8 * hi) ^ (sv << 3))]);
            const bf16x8 vf1 = *reinterpret_cast<const bf16x8*>(
                &Vs[cur][vrow * 64 + ((32 + 8 * hi) ^ (sv << 3))]);
            acc[n] = MFMA(pa0.v, vf0, acc[n]);
            acc[n] = MFMA(pa1.v, vf1, acc[n]);
        }
        __builtin_amdgcn_s_setprio(0);

        SBAR();
    }

    #pragma unroll
    for (int r = 0; r < 4; ++r) {
        const float inv = 1.0f / accL[r];
        const int s = q0 + 16 * wid + 4 * hi + r;
        const size_t base = ((size_t)blockIdx.z * kSEQ + s) * kHID + (size_t)h * kHD;
        #pragma unroll
        for (int n = 0; n < 4; ++n)
            Ob[base + 16 * n + lo] = f2bf(acc[n][r] * inv);
    }
}

}  // namespace

extern "C" void kernel_launch(void* const* d_in, const int* in_sizes, int n_in,
                              void* d_out, int out_size, void* d_ws, size_t ws_size,
                              hipStream_t stream) {
    (void)in_sizes; (void)n_in; (void)out_size;
    const float* x  = (const float*)d_in[0];
    const float* Wq = (const float*)d_in[1];
    const float* bq = (const float*)d_in[2];
    const float* Wk = (const float*)d_in[3];
    const float* bk = (const float*)d_in[4];
    const float* Wv = (const float*)d_in[5];
    const float* bv = (const float*)d_in[6];
    const float* Wo = (const float*)d_in[7];
    const float* bo = (const float*)d_in[8];

    constexpr size_t kXE = (size_t)2 * kSEQ * kHID;   // 4 Mi elems
    constexpr size_t kWE = (size_t)kHID * kHID;       // 1 Mi elems
    const size_t needed = (kXE + 4 * kWE + 3 * kXE + kXE) * sizeof(ushortT);
    if (ws_size < needed) return;

    ushortT* xb    = (ushortT*)d_ws;
    ushortT* WtAll = xb + kXE;
    ushortT* qkvb  = WtAll + 4 * kWE;
    ushortT* attnb = qkvb + 3 * kXE;

    const ushortT* qb  = qkvb;            // [B,H,S,D], pre-scaled by 0.125*log2e
    const ushortT* kb  = qkvb + kXE;      // [B,H,S,D]
    const ushortT* vtb = qkvb + 2 * kXE;  // [B,H,D,S]  (transposed)

    // fused x-convert + weight-transpose (one launch, independent work)
    prep_kernel<<<dim3(4096 + 4 * 256), 256, 0, stream>>>(
        x, xb, Wq, Wk, Wv, Wo, WtAll);

    qkv_mfma_gemm<<<dim3(8, 32, 3), 256, 0, stream>>>(xb, WtAll, bq, bk, bv, qkvb);

    // blockIdx.x = head: linear id % 8 == head % 8 -> head pinned to one XCD.
    flash_mfma_kernel<<<dim3(kNH, kSEQ / 64, 2), 256, 0, stream>>>(qb, kb, vtb, attnb);

    out_mfma_gemm<<<dim3(8, 64), 256, 0, stream>>>(attnb, WtAll + 3 * kWE, bo, (float*)d_out);
}